// Round 5
// baseline (243.679 us; speedup 1.0000x reference)
//
#include <hip/hip_runtime.h>
#include <math.h>

// MultiScaleRetention forward. B=8 S=1024 D=512 H=8 DH=64.
// R5: GEMM A-tile staged fp32 (clean b128 staging, in-register split at frag load),
//     W_O GEMM A-frags direct from global (pre-split Z), GN+gate fused into attention
//     epilogue (gn_gate kernel + 32 MB of Y traffic removed), cheaper P rounding.
#define B_ 8
#define S_ 1024
#define D_ 512
#define H_ 8
#define DH_ 64
#define M_ (B_*S_)   // 8192 rows

typedef __attribute__((ext_vector_type(8))) short short8;
typedef __attribute__((ext_vector_type(4))) short s16x4;
typedef __attribute__((ext_vector_type(4))) float f32x4;

// trunc split: x = hi + lo + O(2^-16 |x|); x - hi is exact in fp32.
__device__ inline void tsplit(float x, short& hs, short& ls) {
  unsigned u = __float_as_uint(x);
  hs = (short)(u >> 16);
  float r = x - __uint_as_float(u & 0xFFFF0000u);
  ls = (short)(__float_as_uint(r) >> 16);
}
__device__ inline f32x4 mfma16(short8 a, short8 b, f32x4 c) {
  return __builtin_amdgcn_mfma_f32_16x16x32_bf16(a, b, c, 0, 0, 0);
}

// ---------- xpos tables: 4 x [1024][32] = cosQ | sinQ | cosK | sinK ----------
__global__ void xpos_table_kernel(float* __restrict__ tab) {
  int idx = blockIdx.x * 256 + threadIdx.x;
  int s = idx >> 5, i = idx & 31;
  float sv = (2.0f * (float)i + 0.4f * 64.0f) / (1.4f * 64.0f);
  float p = (float)s / 512.0f;
  float scale = powf(sv, p);
  float inv_freq = powf(10000.0f, -((float)i / 32.0f));
  float ang = (float)s * inv_freq;
  float sn = sinf(ang), cs = cosf(ang);
  tab[idx]          = cs * scale;
  tab[32768 + idx]  = sn * scale;
  tab[65536 + idx]  = cs / scale;
  tab[98304 + idx]  = sn / scale;
}

// ---------- weight prep: BT[n][k] split bf16 ----------
__global__ __launch_bounds__(256) void wprep_kernel(
    const float* __restrict__ Wq, const float* __restrict__ Wk,
    const float* __restrict__ Wv, const float* __restrict__ Wg,
    short* __restrict__ BTh, short* __restrict__ BTl, int gonly) {
  __shared__ float t[64][65];
  const int n0 = blockIdx.x * 64, k0 = blockIdx.y * 64;
  const int tid = threadIdx.x;
  const float* src;
  int ld;
  if (gonly) {
    src = Wg + (size_t)k0 * 512 + n0; ld = 512;
  } else {
    int w = n0 >> 9, nn = n0 & 511;
    if (w == 3) { src = Wg + (size_t)k0 * 512 + nn; ld = 512; }
    else {
      const float* W = (w == 0) ? Wq : ((w == 1) ? Wk : Wv);
      int h = nn >> 6;
      src = W + (size_t)h * D_ * DH_ + (size_t)k0 * 64; ld = 64;
    }
  }
#pragma unroll
  for (int i = 0; i < 4; ++i) {
    int idx = tid + i * 256;
    int kk = idx >> 4, nl4 = (idx & 15) * 4;
    float4 v = *(const float4*)(src + (size_t)kk * ld + nl4);
    t[kk][nl4] = v.x; t[kk][nl4 + 1] = v.y; t[kk][nl4 + 2] = v.z; t[kk][nl4 + 3] = v.w;
  }
  __syncthreads();
#pragma unroll
  for (int i = 0; i < 2; ++i) {
    int idx = tid + i * 256;
    int nl = idx >> 3, ck = idx & 7;
    short8 hh, ll;
#pragma unroll
    for (int j = 0; j < 8; ++j) {
      short h_, l_;
      tsplit(t[ck * 8 + j][nl], h_, l_);
      hh[j] = h_; ll[j] = l_;
    }
    size_t off = (size_t)(n0 + nl) * 512 + k0 + ck * 8;
    *(short8*)(BTh + off) = hh;
    *(short8*)(BTl + off) = ll;
  }
}

// ---------- split-bf16 MFMA GEMM: C = A * BT^T. 128x128 tile, BK=32 ----------
// AMODE 0: A fp32 from global, staged fp32 in LDS, split in registers at frag load.
// AMODE 1: A pre-split bf16 (Ah/Al) in global, fragments loaded directly (no A LDS).
// fused epilogue: by>>2 = 0:Q 1:K (rotary, split-bf16 [bh][s][e]), 2:V^T split [bh][e][s],
//                 3:G fp32 [m][512].  !fused: fp32 out (G ptr).
template<int AMODE>
__global__ __launch_bounds__(256) void gemm_mfma_kernel(
    const float* __restrict__ Af,
    const short* __restrict__ Ah, const short* __restrict__ Al,
    const short* __restrict__ BTh, const short* __restrict__ BTl,
    const float* __restrict__ tab,
    short* __restrict__ QhO, short* __restrict__ QlO,
    short* __restrict__ KhO, short* __restrict__ KlO,
    short* __restrict__ VhT, short* __restrict__ VlT,
    float* __restrict__ G, int fused) {
  __shared__ __align__(16) float AsF[AMODE == 0 ? 128 : 1][36];  // stride 36 fl: 2-way free
  __shared__ __align__(16) short BsH[128][40];                   // stride 40 sh: 2-way free
  __shared__ __align__(16) short BsL[128][40];
  const int m0 = blockIdx.x * 128, by = blockIdx.y, n0 = by * 128;
  const int tid = threadIdx.x, w = tid >> 6, lane = tid & 63;
  const int lx = lane & 15, quad = lane >> 4;
  const int wr = w >> 1, wc = w & 1;
  f32x4 acc[4][4] = {};
  for (int k0 = 0; k0 < 512; k0 += 32) {
    if constexpr (AMODE == 0) {
      int r = tid >> 1, cb = (tid & 1) * 16;
      const float* ap = Af + (size_t)(m0 + r) * 512 + k0 + cb;
#pragma unroll
      for (int j4 = 0; j4 < 4; ++j4)
        *(float4*)&AsF[r][cb + j4 * 4] = *(const float4*)(ap + j4 * 4);
    }
#pragma unroll
    for (int i = 0; i < 2; ++i) {
      int idx = tid + i * 256;
      int r = idx >> 2, sg = (idx & 3) * 8;
      *(short8*)&BsH[r][sg] = *(const short8*)(BTh + (size_t)(n0 + r) * 512 + k0 + sg);
      *(short8*)&BsL[r][sg] = *(const short8*)(BTl + (size_t)(n0 + r) * 512 + k0 + sg);
    }
    __syncthreads();
    short8 fah[4], fal[4], fbh[4], fbl[4];
#pragma unroll
    for (int i = 0; i < 4; ++i) {
      if constexpr (AMODE == 0) {
        const float* ap2 = &AsF[wr * 64 + i * 16 + lx][quad * 8];
        float4 a = *(const float4*)ap2, c = *(const float4*)(ap2 + 4);
        float xs[8] = {a.x, a.y, a.z, a.w, c.x, c.y, c.z, c.w};
        short8 hh, ll;
#pragma unroll
        for (int j = 0; j < 8; ++j) {
          short h_, l_;
          tsplit(xs[j], h_, l_);
          hh[j] = h_; ll[j] = l_;
        }
        fah[i] = hh; fal[i] = ll;
      } else {
        size_t aoff = (size_t)(m0 + wr * 64 + i * 16 + lx) * 512 + k0 + quad * 8;
        fah[i] = *(const short8*)(Ah + aoff);
        fal[i] = *(const short8*)(Al + aoff);
      }
      fbh[i] = *(const short8*)&BsH[wc * 64 + i * 16 + lx][quad * 8];
      fbl[i] = *(const short8*)&BsL[wc * 64 + i * 16 + lx][quad * 8];
    }
#pragma unroll
    for (int ms = 0; ms < 4; ++ms)
#pragma unroll
      for (int ns = 0; ns < 4; ++ns) {
        f32x4 a = acc[ms][ns];
        a = mfma16(fah[ms], fbh[ns], a);
        a = mfma16(fal[ms], fbh[ns], a);
        a = mfma16(fah[ms], fbl[ns], a);
        acc[ms][ns] = a;
      }
    __syncthreads();
  }
  // ---- epilogue ----
  if (fused) {
    const int w4 = by >> 2;
    const int ncb = (by & 3) * 128 + wc * 64;   // within 512
    if (w4 < 2) {
      short* Ph = (w4 == 0) ? QhO : KhO;
      short* Pl = (w4 == 0) ? QlO : KlO;
      const float* ct = tab + (w4 ? 65536 : 0);
      const float* st = tab + (w4 ? 98304 : 32768);
#pragma unroll
      for (int ms = 0; ms < 4; ++ms) {
        const int m = m0 + wr * 64 + ms * 16 + quad * 4;
        const int b = m >> 10, sbase = m & 1023;
#pragma unroll
        for (int ns = 0; ns < 4; ++ns) {
          const int n = ncb + ns * 16 + lx;
          const int h = n >> 6, e = n & 63;
          const int i0 = e >> 1;
          const float sgn = (e & 1) ? 1.0f : -1.0f;
          short* ph = Ph + (((size_t)(b * 8 + h)) * 1024 + sbase) * 64 + e;
          short* pl = Pl + (((size_t)(b * 8 + h)) * 1024 + sbase) * 64 + e;
#pragma unroll
          for (int rg = 0; rg < 4; ++rg) {
            const int s = sbase + rg;
            float v = acc[ms][ns][rg];
            float vp = __shfl_xor(v, 1);
            float o = v * ct[s * 32 + i0] + sgn * vp * st[s * 32 + i0];
            short h_, l_;
            tsplit(o, h_, l_);
            ph[rg * 64] = h_;
            pl[rg * 64] = l_;
          }
        }
      }
    } else if (w4 == 2) {
#pragma unroll
      for (int ms = 0; ms < 4; ++ms) {
        const int m = m0 + wr * 64 + ms * 16 + quad * 4;
        const int b = m >> 10, s = m & 1023;
#pragma unroll
        for (int ns = 0; ns < 4; ++ns) {
          const int n = ncb + ns * 16 + lx;
          const int h = n >> 6, e = n & 63;
          s16x4 hh, ll;
#pragma unroll
          for (int rg = 0; rg < 4; ++rg) {
            short h_, l_;
            tsplit(acc[ms][ns][rg], h_, l_);
            hh[rg] = h_; ll[rg] = l_;
          }
          size_t off = (((size_t)(b * 8 + h)) * 64 + e) * 1024 + s;
          *(s16x4*)(VhT + off) = hh;
          *(s16x4*)(VlT + off) = ll;
        }
      }
    } else {
#pragma unroll
      for (int ms = 0; ms < 4; ++ms) {
        const int m = m0 + wr * 64 + ms * 16 + quad * 4;
#pragma unroll
        for (int ns = 0; ns < 4; ++ns) {
          const int n = ncb + ns * 16 + lx;
#pragma unroll
          for (int rg = 0; rg < 4; ++rg) G[(size_t)(m + rg) * 512 + n] = acc[ms][ns][rg];
        }
      }
    }
  } else {
#pragma unroll
    for (int ms = 0; ms < 4; ++ms) {
      const int m = m0 + wr * 64 + ms * 16 + quad * 4;
#pragma unroll
      for (int ns = 0; ns < 4; ++ns) {
        const int n = n0 + wc * 64 + ns * 16 + lx;
#pragma unroll
        for (int rg = 0; rg < 4; ++rg) G[(size_t)(m + rg) * 512 + n] = acc[ms][ns][rg];
      }
    }
  }
}

// ---------- attention + GroupNorm + swish-gate, split-bf16 MFMA ----------
// grid (64, 8): x = bh (same-bh s-blocks share an XCD), y = s-tile of 128.
// Epilogue: per-row GN over the head's 64 cols (in-block), gate with swish(G), write split Z.
__global__ __launch_bounds__(256, 2) void attn_mfma_kernel(
    const short* __restrict__ Qh, const short* __restrict__ Ql,
    const short* __restrict__ Kh, const short* __restrict__ Kl,
    const short* __restrict__ VhT, const short* __restrict__ VlT,
    const float* __restrict__ Gp,
    const float* __restrict__ gnw, const float* __restrict__ gnb,
    short* __restrict__ Zh, short* __restrict__ Zl) {
  __shared__ __align__(16) short KhS[64][72];     // [t][e]
  __shared__ __align__(16) short KlS[64][72];
  __shared__ __align__(16) short VhS[64][72];     // [e][t]
  __shared__ __align__(16) short VlS[64][72];
  __shared__ __align__(16) short PhS[4][32][72];  // per-wave [s][t]
  const int bh = blockIdx.x, s0 = blockIdx.y * 128;
  const int b = bh >> 3, h = bh & 7;
  const int tid = threadIdx.x;
  const int w = tid >> 6, lane = tid & 63;
  const int lx = lane & 15, quad = lane >> 4;
  const int s0w = s0 + w * 32;
  const float l0c = -3.4657359027997265f;   // ln(1/32)
  const float l1c = -6.2383246250395075f;   // ln(1/512)
  const float gamma = 1.0f - expf(l0c + (float)h * (l1c - l0c) / 7.0f);
  const float lg2g = log2f(gamma);
  const short* Qbh = Qh + (size_t)bh * S_ * DH_;
  const short* Qbl = Ql + (size_t)bh * S_ * DH_;
  const short* Kbh = Kh + (size_t)bh * S_ * DH_;
  const short* Kbl = Kl + (size_t)bh * S_ * DH_;
  const short* VbH = VhT + (size_t)bh * DH_ * S_;
  const short* VbL = VlT + (size_t)bh * DH_ * S_;

  float cl[4], cr[4], w4g[4], b4g[4];
#pragma unroll
  for (int ns = 0; ns < 4; ++ns) {
    cl[ns] = exp2f(lg2g * (float)(ns * 16 + lx));
    cr[ns] = exp2f(lg2g * (float)(63 - ns * 16 - lx));
    w4g[ns] = gnw[h * DH_ + ns * 16 + lx];
    b4g[ns] = gnb[h * DH_ + ns * 16 + lx];
  }

  // Q A-fragments straight from global (pre-split by GEMM epilogue)
  short8 qfh[2][2], qfl[2][2];
#pragma unroll
  for (int ms = 0; ms < 2; ++ms)
#pragma unroll
    for (int kc = 0; kc < 2; ++kc) {
      size_t off = (size_t)(s0w + ms * 16 + lx) * DH_ + kc * 32 + quad * 8;
      qfh[ms][kc] = *(const short8*)(Qbh + off);
      qfl[ms][kc] = *(const short8*)(Qbl + off);
    }

  f32x4 O[2][4] = {};
  float lsum[2][4] = {};

  for (int t0 = 0; t0 < S_; t0 += 64) {
    __syncthreads();
#pragma unroll
    for (int i = 0; i < 2; ++i) {
      int slot = tid + i * 256;
      int r = slot >> 3, c8 = (slot & 7) * 8;
      *(short8*)&KhS[r][c8] = *(const short8*)(Kbh + (size_t)(t0 + r) * DH_ + c8);
      *(short8*)&KlS[r][c8] = *(const short8*)(Kbl + (size_t)(t0 + r) * DH_ + c8);
      *(short8*)&VhS[r][c8] = *(const short8*)(VbH + (size_t)r * S_ + t0 + c8);
      *(short8*)&VlS[r][c8] = *(const short8*)(VbL + (size_t)r * S_ + t0 + c8);
    }
    __syncthreads();
    // ---- QK^T ----
    f32x4 acc[2][4];
#pragma unroll
    for (int ns = 0; ns < 4; ++ns) {
      short8 kh0 = *(const short8*)&KhS[ns * 16 + lx][quad * 8];
      short8 kh1 = *(const short8*)&KhS[ns * 16 + lx][32 + quad * 8];
      short8 kl0 = *(const short8*)&KlS[ns * 16 + lx][quad * 8];
      short8 kl1 = *(const short8*)&KlS[ns * 16 + lx][32 + quad * 8];
#pragma unroll
      for (int ms = 0; ms < 2; ++ms) {
        f32x4 a = {};
        a = mfma16(qfh[ms][0], kh0, a);
        a = mfma16(qfl[ms][0], kh0, a);
        a = mfma16(qfh[ms][0], kl0, a);
        a = mfma16(qfh[ms][1], kh1, a);
        a = mfma16(qfl[ms][1], kh1, a);
        a = mfma16(qfh[ms][1], kl1, a);
        acc[ms][ns] = a;
      }
    }
    // ---- one-pass softmax numerator (bounded scores), decay into P ----
    const int cse = (t0 + 63 < s0w) ? 0 : ((t0 > s0w + 31) ? 1 : 2);
#pragma unroll
    for (int ms = 0; ms < 2; ++ms)
#pragma unroll
      for (int rg = 0; rg < 4; ++rg) {
        const int rloc = ms * 16 + quad * 4 + rg;
        const int srow = s0w + rloc;
        float pe[4], p[4];
#pragma unroll
        for (int ns = 0; ns < 4; ++ns) pe[ns] = __expf(acc[ms][ns][rg]);
        lsum[ms][rg] += (pe[0] + pe[1]) + (pe[2] + pe[3]);
        if (cse == 0) {
          float rf = exp2f(lg2g * (float)(srow - t0 - 63));
#pragma unroll
          for (int ns = 0; ns < 4; ++ns) p[ns] = pe[ns] * rf * cr[ns];
        } else if (cse == 1) {
          float rf = exp2f(lg2g * (float)(t0 - srow));
#pragma unroll
          for (int ns = 0; ns < 4; ++ns) p[ns] = pe[ns] * rf * cl[ns];
        } else {
#pragma unroll
          for (int ns = 0; ns < 4; ++ns)
            p[ns] = pe[ns] * exp2f(lg2g * fabsf((float)(srow - (t0 + ns * 16 + lx))));
        }
#pragma unroll
        for (int ns = 0; ns < 4; ++ns)
          PhS[w][rloc][ns * 16 + lx] = (short)((__float_as_uint(p[ns]) + 0x8000u) >> 16);
      }
    // ---- PV ----
    short8 pf[2][2];
#pragma unroll
    for (int ms = 0; ms < 2; ++ms)
#pragma unroll
      for (int kc = 0; kc < 2; ++kc)
        pf[ms][kc] = *(const short8*)&PhS[w][ms * 16 + lx][kc * 32 + quad * 8];
#pragma unroll
    for (int ns = 0; ns < 4; ++ns) {
      short8 vh0 = *(const short8*)&VhS[ns * 16 + lx][quad * 8];
      short8 vh1 = *(const short8*)&VhS[ns * 16 + lx][32 + quad * 8];
      short8 vl0 = *(const short8*)&VlS[ns * 16 + lx][quad * 8];
      short8 vl1 = *(const short8*)&VlS[ns * 16 + lx][32 + quad * 8];
#pragma unroll
      for (int ms = 0; ms < 2; ++ms) {
        f32x4 o = O[ms][ns];
        o = mfma16(pf[ms][0], vh0, o);
        o = mfma16(pf[ms][0], vl0, o);
        o = mfma16(pf[ms][1], vh1, o);
        o = mfma16(pf[ms][1], vl1, o);
        O[ms][ns] = o;
      }
    }
  }
  // ---- epilogue: l-normalize, GroupNorm over the head's 64 cols, swish(G) gate, split Z ----
#pragma unroll
  for (int ms = 0; ms < 2; ++ms)
#pragma unroll
    for (int rg = 0; rg < 4; ++rg) {
      float s = lsum[ms][rg];
      s += __shfl_xor(s, 1);
      s += __shfl_xor(s, 2);
      s += __shfl_xor(s, 4);
      s += __shfl_xor(s, 8);
      const float inv = 1.0f / s;
      const int srow = s0w + ms * 16 + quad * 4 + rg;
      float y[4];
      float rs = 0.0f;
#pragma unroll
      for (int ns = 0; ns < 4; ++ns) { y[ns] = O[ms][ns][rg] * inv; rs += y[ns]; }
      rs += __shfl_xor(rs, 1);
      rs += __shfl_xor(rs, 2);
      rs += __shfl_xor(rs, 4);
      rs += __shfl_xor(rs, 8);
      const float mu = rs * (1.0f / 64.0f);
      float vv = 0.0f;
#pragma unroll
      for (int ns = 0; ns < 4; ++ns) { float d = y[ns] - mu; vv += d * d; }
      vv += __shfl_xor(vv, 1);
      vv += __shfl_xor(vv, 2);
      vv += __shfl_xor(vv, 4);
      vv += __shfl_xor(vv, 8);
      const float rstd = rsqrtf(vv * (1.0f / 64.0f) + 1e-5f);
      const size_t base = (size_t)(b * S_ + srow) * D_ + h * DH_;
#pragma unroll
      for (int ns = 0; ns < 4; ++ns) {
        float g = Gp[base + ns * 16 + lx];
        float sw = g / (1.0f + __expf(-g));
        float z = sw * ((y[ns] - mu) * rstd * w4g[ns] + b4g[ns]);
        short zh_, zl_;
        tsplit(z, zh_, zl_);
        Zh[base + ns * 16 + lx] = zh_;
        Zl[base + ns * 16 + lx] = zl_;
      }
    }
}

extern "C" void kernel_launch(void* const* d_in, const int* in_sizes, int n_in,
                              void* d_out, int out_size, void* d_ws, size_t ws_size,
                              hipStream_t stream) {
  const float* X   = (const float*)d_in[0];
  const float* Wq  = (const float*)d_in[1];
  const float* Wk  = (const float*)d_in[2];
  const float* Wv  = (const float*)d_in[3];
  const float* Wg  = (const float*)d_in[4];
  const float* Wo  = (const float*)d_in[5];
  const float* gnw = (const float*)d_in[6];
  const float* gnb = (const float*)d_in[7];
  float* out = (float*)d_out;
  float* ws  = (float*)d_ws;
  const size_t NB = (size_t)M_ * D_;   // 4M elems
  // Region lifetimes (stream-ordered):
  //  R0: Qh/Ql (live through attn)
  //  R1: Kh/Kl (dies at attn end) -> BToh/BTol
  //  R2: VhT/VlT (live through attn)
  //  R3: BT fused (dies after proj GEMM) -> Zh/Zl (attn out)
  //  out: G fp32 (proj out, read by attn) -> final output (WO GEMM)
  float* R0 = ws;
  float* R1 = ws + NB;
  float* R2 = ws + 2 * NB;
  float* R3 = ws + 3 * NB;
  float* tab = ws + 4 * NB;
  short* BTh = (short*)R3;
  short* BTl = BTh + (size_t)2048 * 512;
  short* Qh = (short*)R0;  short* Ql = Qh + NB;
  short* Kh = (short*)R1;  short* Kl = Kh + NB;
  short* VhT = (short*)R2; short* VlT = VhT + NB;
  short* Zh = (short*)R3;  short* Zl = Zh + NB;
  short* BToh = (short*)R1;
  short* BTol = BToh + (size_t)512 * 512;

  wprep_kernel<<<dim3(32, 8), 256, 0, stream>>>(Wq, Wk, Wv, Wg, BTh, BTl, 0);
  xpos_table_kernel<<<128, 256, 0, stream>>>(tab);
  gemm_mfma_kernel<0><<<dim3(64, 16), 256, 0, stream>>>(
      X, nullptr, nullptr, BTh, BTl, tab, Qh, Ql, Kh, Kl, VhT, VlT, out, 1);
  attn_mfma_kernel<<<dim3(64, 8), 256, 0, stream>>>(
      Qh, Ql, Kh, Kl, VhT, VlT, out, gnw, gnb, Zh, Zl);
  wprep_kernel<<<dim3(8, 8), 256, 0, stream>>>(nullptr, nullptr, nullptr, Wo, BToh, BTol, 1);
  gemm_mfma_kernel<1><<<dim3(64, 4), 256, 0, stream>>>(
      nullptr, Zh, Zl, BToh, BTol, nullptr, nullptr, nullptr, nullptr, nullptr,
      nullptr, nullptr, out, 0);
}

// Round 6
// 229.013 us; speedup vs baseline: 1.0640x; 1.0640x over previous
//
#include <hip/hip_runtime.h>
#include <math.h>

// MultiScaleRetention forward. B=8 S=1024 D=512 H=8 DH=64.
// R6: split-at-staging (once per element, b128 writes), global_load_lds width=16
//     for all pre-split operands, W_O GEMM re-tiled to 128x64 (2 blocks/CU, LDS-staged).
#define B_ 8
#define S_ 1024
#define D_ 512
#define H_ 8
#define DH_ 64
#define M_ (B_*S_)   // 8192 rows

typedef __attribute__((ext_vector_type(8))) short short8;
typedef __attribute__((ext_vector_type(4))) short s16x4;
typedef __attribute__((ext_vector_type(4))) float f32x4;

// trunc split: x = hi + lo + O(2^-16 |x|); x - hi is exact in fp32.
__device__ inline void tsplit(float x, short& hs, short& ls) {
  unsigned u = __float_as_uint(x);
  hs = (short)(u >> 16);
  float r = x - __uint_as_float(u & 0xFFFF0000u);
  ls = (short)(__float_as_uint(r) >> 16);
}
__device__ inline f32x4 mfma16(short8 a, short8 b, f32x4 c) {
  return __builtin_amdgcn_mfma_f32_16x16x32_bf16(a, b, c, 0, 0, 0);
}
// async global->LDS, 16B per lane; LDS dst = wave-uniform base + lane*16
__device__ inline void gload_lds16(const void* g, void* l) {
  __builtin_amdgcn_global_load_lds(
      (const __attribute__((address_space(1))) void*)g,
      (__attribute__((address_space(3))) void*)l, 16, 0, 0);
}

// ---------- xpos tables: 4 x [1024][32] = cosQ | sinQ | cosK | sinK ----------
__global__ void xpos_table_kernel(float* __restrict__ tab) {
  int idx = blockIdx.x * 256 + threadIdx.x;
  int s = idx >> 5, i = idx & 31;
  float sv = (2.0f * (float)i + 0.4f * 64.0f) / (1.4f * 64.0f);
  float p = (float)s / 512.0f;
  float scale = powf(sv, p);
  float inv_freq = powf(10000.0f, -((float)i / 32.0f));
  float ang = (float)s * inv_freq;
  float sn = sinf(ang), cs = cosf(ang);
  tab[idx]          = cs * scale;
  tab[32768 + idx]  = sn * scale;
  tab[65536 + idx]  = cs / scale;
  tab[98304 + idx]  = sn / scale;
}

// ---------- weight prep: BT[n][k] split bf16 ----------
__global__ __launch_bounds__(256) void wprep_kernel(
    const float* __restrict__ Wq, const float* __restrict__ Wk,
    const float* __restrict__ Wv, const float* __restrict__ Wg,
    short* __restrict__ BTh, short* __restrict__ BTl, int gonly) {
  __shared__ float t[64][65];
  const int n0 = blockIdx.x * 64, k0 = blockIdx.y * 64;
  const int tid = threadIdx.x;
  const float* src;
  int ld;
  if (gonly) {
    src = Wg + (size_t)k0 * 512 + n0; ld = 512;
  } else {
    int w = n0 >> 9, nn = n0 & 511;
    if (w == 3) { src = Wg + (size_t)k0 * 512 + nn; ld = 512; }
    else {
      const float* W = (w == 0) ? Wq : ((w == 1) ? Wk : Wv);
      int h = nn >> 6;
      src = W + (size_t)h * D_ * DH_ + (size_t)k0 * 64; ld = 64;
    }
  }
#pragma unroll
  for (int i = 0; i < 4; ++i) {
    int idx = tid + i * 256;
    int kk = idx >> 4, nl4 = (idx & 15) * 4;
    float4 v = *(const float4*)(src + (size_t)kk * ld + nl4);
    t[kk][nl4] = v.x; t[kk][nl4 + 1] = v.y; t[kk][nl4 + 2] = v.z; t[kk][nl4 + 3] = v.w;
  }
  __syncthreads();
#pragma unroll
  for (int i = 0; i < 2; ++i) {
    int idx = tid + i * 256;
    int nl = idx >> 3, ck = idx & 7;
    short8 hh, ll;
#pragma unroll
    for (int j = 0; j < 8; ++j) {
      short h_, l_;
      tsplit(t[ck * 8 + j][nl], h_, l_);
      hh[j] = h_; ll[j] = l_;
    }
    size_t off = (size_t)(n0 + nl) * 512 + k0 + ck * 8;
    *(short8*)(BTh + off) = hh;
    *(short8*)(BTl + off) = ll;
  }
}

// ---------- split-bf16 MFMA GEMM: C = A * BT^T. BK=32 ----------
// AMODE 0: A fp32 from global, tsplit at staging (once/element), b128 LDS writes.
// AMODE 1: A pre-split bf16 in global, staged via global_load_lds (no VGPR round-trip).
// NSUB: n-subtiles per wave (4 -> 128-wide n-tile, 2 -> 64-wide).
// fused epilogue (NSUB=4): by>>2 = 0:Q 1:K (rotary, split [bh][s][e]), 2:V^T split
// [bh][e][s], 3:G fp32 [m][512].  !fused: fp32 out (G ptr).
template<int AMODE, int NSUB>
__global__ __launch_bounds__(256) void gemm_mfma_kernel(
    const float* __restrict__ Af,
    const short* __restrict__ Ah, const short* __restrict__ Al,
    const short* __restrict__ BTh, const short* __restrict__ BTl,
    const float* __restrict__ tab,
    short* __restrict__ QhO, short* __restrict__ QlO,
    short* __restrict__ KhO, short* __restrict__ KlO,
    short* __restrict__ VhT, short* __restrict__ VlT,
    float* __restrict__ G, int fused) {
  constexpr int NT = NSUB * 32;                 // n rows per block
  constexpr int ASTR = (AMODE == 0) ? 40 : 32;  // A LDS row stride (shorts)
  __shared__ __align__(16) short AsH[128][ASTR];
  __shared__ __align__(16) short AsL[128][ASTR];
  __shared__ __align__(16) short BsH[NT][32];   // 64B rows, global_load_lds target
  __shared__ __align__(16) short BsL[NT][32];
  const int m0 = blockIdx.x * 128, by = blockIdx.y, n0 = by * NT;
  const int tid = threadIdx.x, w = tid >> 6, lane = tid & 63;
  const int lx = lane & 15, quad = lane >> 4;
  const int wr = w >> 1, wc = w & 1;
  f32x4 acc[4][NSUB] = {};
  for (int k0 = 0; k0 < 512; k0 += 32) {
    // ---- stage A ----
    if constexpr (AMODE == 0) {
      int r = tid >> 1, cb = (tid & 1) * 16;
      const float* ap = Af + (size_t)(m0 + r) * 512 + k0 + cb;
      short8 hh[2], ll[2];
#pragma unroll
      for (int j4 = 0; j4 < 4; ++j4) {
        float4 v = *(const float4*)(ap + j4 * 4);
        short h_, l_;
        tsplit(v.x, h_, l_); hh[j4 >> 1][(j4 & 1) * 4 + 0] = h_; ll[j4 >> 1][(j4 & 1) * 4 + 0] = l_;
        tsplit(v.y, h_, l_); hh[j4 >> 1][(j4 & 1) * 4 + 1] = h_; ll[j4 >> 1][(j4 & 1) * 4 + 1] = l_;
        tsplit(v.z, h_, l_); hh[j4 >> 1][(j4 & 1) * 4 + 2] = h_; ll[j4 >> 1][(j4 & 1) * 4 + 2] = l_;
        tsplit(v.w, h_, l_); hh[j4 >> 1][(j4 & 1) * 4 + 3] = h_; ll[j4 >> 1][(j4 & 1) * 4 + 3] = l_;
      }
      *(short8*)&AsH[r][cb]     = hh[0];
      *(short8*)&AsH[r][cb + 8] = hh[1];
      *(short8*)&AsL[r][cb]     = ll[0];
      *(short8*)&AsL[r][cb + 8] = ll[1];
    } else {
      // 8 chunks of 16 rows x 64B per array; 2 chunks per wave per array
#pragma unroll
      for (int c = 0; c < 2; ++c) {
        int ch = w + c * 4;
        size_t goff = (size_t)(m0 + ch * 16 + (lane >> 2)) * 512 + k0 + (lane & 3) * 8;
        gload_lds16(Ah + goff, &AsH[ch * 16][0]);
        gload_lds16(Al + goff, &AsL[ch * 16][0]);
      }
    }
    // ---- stage B via global_load_lds ----
    {
      constexpr int NCH = NT / 16;
#pragma unroll
      for (int ch = 0; ch < NCH; ch += 4) {
        int c = w + ch;
        if (c < NCH) {
          size_t goff = (size_t)(n0 + c * 16 + (lane >> 2)) * 512 + k0 + (lane & 3) * 8;
          gload_lds16(BTh + goff, &BsH[c * 16][0]);
          gload_lds16(BTl + goff, &BsL[c * 16][0]);
        }
      }
    }
    __syncthreads();
    short8 fah[4], fal[4], fbh[NSUB], fbl[NSUB];
#pragma unroll
    for (int i = 0; i < 4; ++i) {
      fah[i] = *(const short8*)&AsH[wr * 64 + i * 16 + lx][quad * 8];
      fal[i] = *(const short8*)&AsL[wr * 64 + i * 16 + lx][quad * 8];
    }
#pragma unroll
    for (int i = 0; i < NSUB; ++i) {
      fbh[i] = *(const short8*)&BsH[wc * (NSUB * 16) + i * 16 + lx][quad * 8];
      fbl[i] = *(const short8*)&BsL[wc * (NSUB * 16) + i * 16 + lx][quad * 8];
    }
#pragma unroll
    for (int ms = 0; ms < 4; ++ms)
#pragma unroll
      for (int ns = 0; ns < NSUB; ++ns) {
        f32x4 a = acc[ms][ns];
        a = mfma16(fah[ms], fbh[ns], a);
        a = mfma16(fal[ms], fbh[ns], a);
        a = mfma16(fah[ms], fbl[ns], a);
        acc[ms][ns] = a;
      }
    __syncthreads();
  }
  // ---- epilogue ----
  if (fused) {
    const int w4 = by >> 2;
    const int ncb = (by & 3) * 128 + wc * 64;   // within 512
    if (w4 < 2) {
      short* Ph = (w4 == 0) ? QhO : KhO;
      short* Pl = (w4 == 0) ? QlO : KlO;
      const float* ct = tab + (w4 ? 65536 : 0);
      const float* st = tab + (w4 ? 98304 : 32768);
#pragma unroll
      for (int ms = 0; ms < 4; ++ms) {
        const int m = m0 + wr * 64 + ms * 16 + quad * 4;
        const int b = m >> 10, sbase = m & 1023;
#pragma unroll
        for (int ns = 0; ns < 4; ++ns) {
          const int n = ncb + ns * 16 + lx;
          const int h = n >> 6, e = n & 63;
          const int i0 = e >> 1;
          const float sgn = (e & 1) ? 1.0f : -1.0f;
          short* ph = Ph + (((size_t)(b * 8 + h)) * 1024 + sbase) * 64 + e;
          short* pl = Pl + (((size_t)(b * 8 + h)) * 1024 + sbase) * 64 + e;
#pragma unroll
          for (int rg = 0; rg < 4; ++rg) {
            const int s = sbase + rg;
            float v = acc[ms][ns][rg];
            float vp = __shfl_xor(v, 1);
            float o = v * ct[s * 32 + i0] + sgn * vp * st[s * 32 + i0];
            short h_, l_;
            tsplit(o, h_, l_);
            ph[rg * 64] = h_;
            pl[rg * 64] = l_;
          }
        }
      }
    } else if (w4 == 2) {
#pragma unroll
      for (int ms = 0; ms < 4; ++ms) {
        const int m = m0 + wr * 64 + ms * 16 + quad * 4;
        const int b = m >> 10, s = m & 1023;
#pragma unroll
        for (int ns = 0; ns < 4; ++ns) {
          const int n = ncb + ns * 16 + lx;
          const int h = n >> 6, e = n & 63;
          s16x4 hh, ll;
#pragma unroll
          for (int rg = 0; rg < 4; ++rg) {
            short h_, l_;
            tsplit(acc[ms][ns][rg], h_, l_);
            hh[rg] = h_; ll[rg] = l_;
          }
          size_t off = (((size_t)(b * 8 + h)) * 64 + e) * 1024 + s;
          *(s16x4*)(VhT + off) = hh;
          *(s16x4*)(VlT + off) = ll;
        }
      }
    } else {
#pragma unroll
      for (int ms = 0; ms < 4; ++ms) {
        const int m = m0 + wr * 64 + ms * 16 + quad * 4;
#pragma unroll
        for (int ns = 0; ns < 4; ++ns) {
          const int n = ncb + ns * 16 + lx;
#pragma unroll
          for (int rg = 0; rg < 4; ++rg) G[(size_t)(m + rg) * 512 + n] = acc[ms][ns][rg];
        }
      }
    }
  } else {
#pragma unroll
    for (int ms = 0; ms < 4; ++ms) {
      const int m = m0 + wr * 64 + ms * 16 + quad * 4;
#pragma unroll
      for (int ns = 0; ns < NSUB; ++ns) {
        const int n = n0 + wc * (NSUB * 16) + ns * 16 + lx;
#pragma unroll
        for (int rg = 0; rg < 4; ++rg) G[(size_t)(m + rg) * 512 + n] = acc[ms][ns][rg];
      }
    }
  }
}

// ---------- attention + GroupNorm + swish-gate, split-bf16 MFMA ----------
// grid (64, 8): x = bh (same-bh s-blocks share an XCD), y = s-tile of 128.
__global__ __launch_bounds__(256, 2) void attn_mfma_kernel(
    const short* __restrict__ Qh, const short* __restrict__ Ql,
    const short* __restrict__ Kh, const short* __restrict__ Kl,
    const short* __restrict__ VhT, const short* __restrict__ VlT,
    const float* __restrict__ Gp,
    const float* __restrict__ gnw, const float* __restrict__ gnb,
    short* __restrict__ Zh, short* __restrict__ Zl) {
  __shared__ __align__(16) short KhS[64][72];     // [t][e]
  __shared__ __align__(16) short KlS[64][72];
  __shared__ __align__(16) short VhS[64][72];     // [e][t]
  __shared__ __align__(16) short VlS[64][72];
  __shared__ __align__(16) short PhS[4][32][72];  // per-wave [s][t]
  const int bh = blockIdx.x, s0 = blockIdx.y * 128;
  const int b = bh >> 3, h = bh & 7;
  const int tid = threadIdx.x;
  const int w = tid >> 6, lane = tid & 63;
  const int lx = lane & 15, quad = lane >> 4;
  const int s0w = s0 + w * 32;
  const float l0c = -3.4657359027997265f;   // ln(1/32)
  const float l1c = -6.2383246250395075f;   // ln(1/512)
  const float gamma = 1.0f - expf(l0c + (float)h * (l1c - l0c) / 7.0f);
  const float lg2g = log2f(gamma);
  const short* Qbh = Qh + (size_t)bh * S_ * DH_;
  const short* Qbl = Ql + (size_t)bh * S_ * DH_;
  const short* Kbh = Kh + (size_t)bh * S_ * DH_;
  const short* Kbl = Kl + (size_t)bh * S_ * DH_;
  const short* VbH = VhT + (size_t)bh * DH_ * S_;
  const short* VbL = VlT + (size_t)bh * DH_ * S_;

  float cl[4], cr[4], w4g[4], b4g[4];
#pragma unroll
  for (int ns = 0; ns < 4; ++ns) {
    cl[ns] = exp2f(lg2g * (float)(ns * 16 + lx));
    cr[ns] = exp2f(lg2g * (float)(63 - ns * 16 - lx));
    w4g[ns] = gnw[h * DH_ + ns * 16 + lx];
    b4g[ns] = gnb[h * DH_ + ns * 16 + lx];
  }

  short8 qfh[2][2], qfl[2][2];
#pragma unroll
  for (int ms = 0; ms < 2; ++ms)
#pragma unroll
    for (int kc = 0; kc < 2; ++kc) {
      size_t off = (size_t)(s0w + ms * 16 + lx) * DH_ + kc * 32 + quad * 8;
      qfh[ms][kc] = *(const short8*)(Qbh + off);
      qfl[ms][kc] = *(const short8*)(Qbl + off);
    }

  f32x4 O[2][4] = {};
  float lsum[2][4] = {};

  for (int t0 = 0; t0 < S_; t0 += 64) {
    __syncthreads();
#pragma unroll
    for (int i = 0; i < 2; ++i) {
      int slot = tid + i * 256;
      int r = slot >> 3, c8 = (slot & 7) * 8;
      *(short8*)&KhS[r][c8] = *(const short8*)(Kbh + (size_t)(t0 + r) * DH_ + c8);
      *(short8*)&KlS[r][c8] = *(const short8*)(Kbl + (size_t)(t0 + r) * DH_ + c8);
      *(short8*)&VhS[r][c8] = *(const short8*)(VbH + (size_t)r * S_ + t0 + c8);
      *(short8*)&VlS[r][c8] = *(const short8*)(VbL + (size_t)r * S_ + t0 + c8);
    }
    __syncthreads();
    // ---- QK^T ----
    f32x4 acc[2][4];
#pragma unroll
    for (int ns = 0; ns < 4; ++ns) {
      short8 kh0 = *(const short8*)&KhS[ns * 16 + lx][quad * 8];
      short8 kh1 = *(const short8*)&KhS[ns * 16 + lx][32 + quad * 8];
      short8 kl0 = *(const short8*)&KlS[ns * 16 + lx][quad * 8];
      short8 kl1 = *(const short8*)&KlS[ns * 16 + lx][32 + quad * 8];
#pragma unroll
      for (int ms = 0; ms < 2; ++ms) {
        f32x4 a = {};
        a = mfma16(qfh[ms][0], kh0, a);
        a = mfma16(qfl[ms][0], kh0, a);
        a = mfma16(qfh[ms][0], kl0, a);
        a = mfma16(qfh[ms][1], kh1, a);
        a = mfma16(qfl[ms][1], kh1, a);
        a = mfma16(qfh[ms][1], kl1, a);
        acc[ms][ns] = a;
      }
    }
    // ---- one-pass softmax numerator (bounded scores), decay into P ----
    const int cse = (t0 + 63 < s0w) ? 0 : ((t0 > s0w + 31) ? 1 : 2);
#pragma unroll
    for (int ms = 0; ms < 2; ++ms)
#pragma unroll
      for (int rg = 0; rg < 4; ++rg) {
        const int rloc = ms * 16 + quad * 4 + rg;
        const int srow = s0w + rloc;
        float pe[4], p[4];
#pragma unroll
        for (int ns = 0; ns < 4; ++ns) pe[ns] = __expf(acc[ms][ns][rg]);
        lsum[ms][rg] += (pe[0] + pe[1]) + (pe[2] + pe[3]);
        if (cse == 0) {
          float rf = exp2f(lg2g * (float)(srow - t0 - 63));
#pragma unroll
          for (int ns = 0; ns < 4; ++ns) p[ns] = pe[ns] * rf * cr[ns];
        } else if (cse == 1) {
          float rf = exp2f(lg2g * (float)(t0 - srow));
#pragma unroll
          for (int ns = 0; ns < 4; ++ns) p[ns] = pe[ns] * rf * cl[ns];
        } else {
#pragma unroll
          for (int ns = 0; ns < 4; ++ns)
            p[ns] = pe[ns] * exp2f(lg2g * fabsf((float)(srow - (t0 + ns * 16 + lx))));
        }
#pragma unroll
        for (int ns = 0; ns < 4; ++ns)
          PhS[w][rloc][ns * 16 + lx] = (short)((__float_as_uint(p[ns]) + 0x8000u) >> 16);
      }
    // ---- PV ----
    short8 pf[2][2];
#pragma unroll
    for (int ms = 0; ms < 2; ++ms)
#pragma unroll
      for (int kc = 0; kc < 2; ++kc)
        pf[ms][kc] = *(const short8*)&PhS[w][ms * 16 + lx][kc * 32 + quad * 8];
#pragma unroll
    for (int ns = 0; ns < 4; ++ns) {
      short8 vh0 = *(const short8*)&VhS[ns * 16 + lx][quad * 8];
      short8 vh1 = *(const short8*)&VhS[ns * 16 + lx][32 + quad * 8];
      short8 vl0 = *(const short8*)&VlS[ns * 16 + lx][quad * 8];
      short8 vl1 = *(const short8*)&VlS[ns * 16 + lx][32 + quad * 8];
#pragma unroll
      for (int ms = 0; ms < 2; ++ms) {
        f32x4 o = O[ms][ns];
        o = mfma16(pf[ms][0], vh0, o);
        o = mfma16(pf[ms][0], vl0, o);
        o = mfma16(pf[ms][1], vh1, o);
        o = mfma16(pf[ms][1], vl1, o);
        O[ms][ns] = o;
      }
    }
  }
  // ---- epilogue: l-normalize, GroupNorm over head cols, swish(G) gate, split Z ----
#pragma unroll
  for (int ms = 0; ms < 2; ++ms)
#pragma unroll
    for (int rg = 0; rg < 4; ++rg) {
      float s = lsum[ms][rg];
      s += __shfl_xor(s, 1);
      s += __shfl_xor(s, 2);
      s += __shfl_xor(s, 4);
      s += __shfl_xor(s, 8);
      const float inv = 1.0f / s;
      const int srow = s0w + ms * 16 + quad * 4 + rg;
      float y[4];
      float rs = 0.0f;
#pragma unroll
      for (int ns = 0; ns < 4; ++ns) { y[ns] = O[ms][ns][rg] * inv; rs += y[ns]; }
      rs += __shfl_xor(rs, 1);
      rs += __shfl_xor(rs, 2);
      rs += __shfl_xor(rs, 4);
      rs += __shfl_xor(rs, 8);
      const float mu = rs * (1.0f / 64.0f);
      float vv = 0.0f;
#pragma unroll
      for (int ns = 0; ns < 4; ++ns) { float d = y[ns] - mu; vv += d * d; }
      vv += __shfl_xor(vv, 1);
      vv += __shfl_xor(vv, 2);
      vv += __shfl_xor(vv, 4);
      vv += __shfl_xor(vv, 8);
      const float rstd = rsqrtf(vv * (1.0f / 64.0f) + 1e-5f);
      const size_t base = (size_t)(b * S_ + srow) * D_ + h * DH_;
#pragma unroll
      for (int ns = 0; ns < 4; ++ns) {
        float g = Gp[base + ns * 16 + lx];
        float sw = g / (1.0f + __expf(-g));
        float z = sw * ((y[ns] - mu) * rstd * w4g[ns] + b4g[ns]);
        short zh_, zl_;
        tsplit(z, zh_, zl_);
        Zh[base + ns * 16 + lx] = zh_;
        Zl[base + ns * 16 + lx] = zl_;
      }
    }
}

extern "C" void kernel_launch(void* const* d_in, const int* in_sizes, int n_in,
                              void* d_out, int out_size, void* d_ws, size_t ws_size,
                              hipStream_t stream) {
  const float* X   = (const float*)d_in[0];
  const float* Wq  = (const float*)d_in[1];
  const float* Wk  = (const float*)d_in[2];
  const float* Wv  = (const float*)d_in[3];
  const float* Wg  = (const float*)d_in[4];
  const float* Wo  = (const float*)d_in[5];
  const float* gnw = (const float*)d_in[6];
  const float* gnb = (const float*)d_in[7];
  float* out = (float*)d_out;
  float* ws  = (float*)d_ws;
  const size_t NB = (size_t)M_ * D_;   // 4M elems
  // Region lifetimes (stream-ordered):
  //  R0: Qh/Ql (live through attn)
  //  R1: Kh/Kl (dies at attn end) -> BToh/BTol
  //  R2: VhT/VlT (live through attn)
  //  R3: BT fused (dies after proj GEMM) -> Zh/Zl (attn out)
  //  out: G fp32 (proj out, read by attn) -> final output (WO GEMM)
  float* R0 = ws;
  float* R1 = ws + NB;
  float* R2 = ws + 2 * NB;
  float* R3 = ws + 3 * NB;
  float* tab = ws + 4 * NB;
  short* BTh = (short*)R3;
  short* BTl = BTh + (size_t)2048 * 512;
  short* Qh = (short*)R0;  short* Ql = Qh + NB;
  short* Kh = (short*)R1;  short* Kl = Kh + NB;
  short* VhT = (short*)R2; short* VlT = VhT + NB;
  short* Zh = (short*)R3;  short* Zl = Zh + NB;
  short* BToh = (short*)R1;
  short* BTol = BToh + (size_t)512 * 512;

  wprep_kernel<<<dim3(32, 8), 256, 0, stream>>>(Wq, Wk, Wv, Wg, BTh, BTl, 0);
  xpos_table_kernel<<<128, 256, 0, stream>>>(tab);
  gemm_mfma_kernel<0, 4><<<dim3(64, 16), 256, 0, stream>>>(
      X, nullptr, nullptr, BTh, BTl, tab, Qh, Ql, Kh, Kl, VhT, VlT, out, 1);
  attn_mfma_kernel<<<dim3(64, 8), 256, 0, stream>>>(
      Qh, Ql, Kh, Kl, VhT, VlT, out, gnw, gnb, Zh, Zl);
  wprep_kernel<<<dim3(8, 8), 256, 0, stream>>>(nullptr, nullptr, nullptr, Wo, BToh, BTol, 1);
  gemm_mfma_kernel<1, 2><<<dim3(64, 8), 256, 0, stream>>>(
      nullptr, Zh, Zl, BToh, BTol, nullptr, nullptr, nullptr, nullptr, nullptr,
      nullptr, nullptr, out, 0);
}